// Round 1
// baseline (228.550 us; speedup 1.0000x reference)
//
#include <hip/hip_runtime.h>

#define HOG_PI 3.14159265358979323846f

// One workgroup per image. 256 threads: thread t owns half of cell (t>>1)
// (half = t&1 selects upper/lower 8 rows of the 16x16 cell).
// H=256, W=128, 3 channels (NCHW), 16x8 cells, 15x7 blocks, 9 bins.
__global__ __launch_bounds__(256) void hog_kernel(
    const float* __restrict__ img, const int* __restrict__ targets,
    const int* __restrict__ camid, float* __restrict__ out, int B) {
  const int b = blockIdx.x;
  const int t = threadIdx.x;
  const float* im = img + (size_t)b * (3 * 256 * 128);

  __shared__ float part[256][9];   // per-thread private partial histograms
  __shared__ float cellh[128][9];  // final per-cell histograms [cy*8+cx][bin]

#pragma unroll
  for (int k = 0; k < 9; ++k) part[t][k] = 0.0f;
  __syncthreads();

  const int cellid = t >> 1;
  const int half = t & 1;
  const int cy = cellid >> 3;
  const int cx = cellid & 7;
  const int y0 = cy * 16 + half * 8;
  const int x0 = cx * 16;

  for (int r = 0; r < 8; ++r) {
    const int y = y0 + r;
    const int ym = (y == 0) ? 0 : y - 1;
    const int yp = (y == 255) ? 255 : y + 1;
    const float* row0 = im + y * 128;
    const float* row1 = row0 + 32768;
    const float* row2 = row0 + 65536;
    const float* rm0 = im + ym * 128;
    const float* rm1 = rm0 + 32768;
    const float* rm2 = rm0 + 65536;
    const float* rp0 = im + yp * 128;
    const float* rp1 = rp0 + 32768;
    const float* rp2 = rp0 + 65536;
    const int xl = (x0 == 0) ? 0 : x0 - 1;
    // rolling window for dx: left, mid per channel
    float l0 = row0[xl], l1 = row1[xl], l2 = row2[xl];
    float m0 = row0[x0], m1 = row1[x0], m2 = row2[x0];
#pragma unroll
    for (int i = 0; i < 16; ++i) {
      const int x = x0 + i;
      const int xp = (x == 127) ? 127 : x + 1;
      const float r0v = row0[xp], r1v = row1[xp], r2v = row2[xp];
      const float dx0 = r0v - l0, dx1 = r1v - l1, dx2 = r2v - l2;
      const float dy0 = rp0[x] - rm0[x];
      const float dy1 = rp1[x] - rm1[x];
      const float dy2 = rp2[x] - rm2[x];
      l0 = m0; m0 = r0v;
      l1 = m1; m1 = r1v;
      l2 = m2; m2 = r2v;
      const float g0 = dx0 * dx0 + dy0 * dy0;
      const float g1 = dx1 * dx1 + dy1 * dy1;
      const float g2 = dx2 * dx2 + dy2 * dy2;
      // argmax over channels, first-max wins on ties (strict >)
      float dxs = dx0, dys = dy0, g = g0;
      if (g1 > g) { dxs = dx1; dys = dy1; g = g1; }
      if (g2 > g) { dxs = dx2; dys = dy2; g = g2; }
      const float mag = sqrtf(g);
      float ang = atan2f(dys, dxs);
      if (ang < 0.0f) ang += HOG_PI;            // mod pi -> [0, pi)
      const float pos = ang * (9.0f / HOG_PI) - 0.5f;
      const float bf = floorf(pos);
      const float frac = pos - bf;
      const int b0 = (int)bf;                   // in [-1, 8]
      const int b0i = (b0 < 0) ? 8 : b0;
      const int b1i = (b0i == 8) ? 0 : b0i + 1;
      // thread-private LDS rows: ds_add_f32, no contention, no scratch
      atomicAdd(&part[t][b0i], mag * (1.0f - frac));
      atomicAdd(&part[t][b1i], mag * frac);
    }
  }
  __syncthreads();

  if (t < 128) {
#pragma unroll
    for (int k = 0; k < 9; ++k) cellh[t][k] = part[2 * t][k] + part[2 * t + 1][k];
  }
  __syncthreads();

  float* outF = out + (size_t)b * 4096;
  if (t < 105) {
    const int by = t / 7;
    const int bx = t - by * 7;
    const int c00 = by * 8 + bx;
    float v[36];
#pragma unroll
    for (int q = 0; q < 4; ++q) {
      const int cc = c00 + (q & 1) + (q >> 1) * 8;
#pragma unroll
      for (int k = 0; k < 9; ++k) v[q * 9 + k] = cellh[cc][k];
    }
    float ss = 0.0f;
#pragma unroll
    for (int j = 0; j < 36; ++j) ss += v[j] * v[j];
    const float s1 = 1.0f / (sqrtf(ss) + 3.6f);  // sz*0.1 = 36*0.1
    float ss2 = 0.0f;
#pragma unroll
    for (int j = 0; j < 36; ++j) {
      v[j] = fminf(v[j] * s1, 0.2f);
      ss2 += v[j] * v[j];
    }
    const float s2 = 1.0f / (sqrtf(ss2) + 1e-3f);
#pragma unroll
    for (int j = 0; j < 36; ++j) outF[t * 36 + j] = v[j] * s2;
  }
  // zero the pad region [3780, 4096)
  for (int i = 3780 + t; i < 4096; i += 256) outF[i] = 0.0f;
  // passthrough outputs (as float32, concatenated after feat)
  if (t == 128) out[(size_t)B * 4096 + b] = (float)targets[b];
  if (t == 129) out[(size_t)B * 4096 + B + b] = (float)camid[b];
}

extern "C" void kernel_launch(void* const* d_in, const int* in_sizes, int n_in,
                              void* d_out, int out_size, void* d_ws, size_t ws_size,
                              hipStream_t stream) {
  const float* images = (const float*)d_in[0];
  const int* targets = (const int*)d_in[1];
  const int* camid = (const int*)d_in[2];
  float* out = (float*)d_out;
  const int B = in_sizes[1];  // 512
  hipLaunchKernelGGL(hog_kernel, dim3(B), dim3(256), 0, stream,
                     images, targets, camid, out, B);
}